// Round 4
// baseline (136.246 us; speedup 1.0000x reference)
//
#include <hip/hip_runtime.h>
#include <hip/hip_fp16.h>

// QLinear with per-k fp16 requantized accumulation (mptorch fma semantics).
// out = q16( q16_scan_fma( q8(x) @ q8(W)^T ) + q8(b) )
//
// Round-4: lane tile 8m x 2n (area 16 -> 8 waves/CU preserved).
//  - w: one ds_read_b64 per k-pair (8 B/lane, 512 B/wave, 2-way = free):
//    LDS return traffic halves vs b128. Layout wP[K/2][N/2][2] u32 =
//    {k0 n-pair, k1 n-pair}.
//  - x: wave-uniform (all lanes same 8 m-rows) -> streams from GLOBAL on the
//    idle VMEM pipe, prefetched one 8-k-pair group ahead into ping-pong
//    register buffers (static indexing). Layout xPw[M/8][K/2][8] u32 makes
//    each wave's k-stream contiguous (16 KB per wave, L2-resident).
// Per-CU round: LDS 48 cyc, VALU 64 cyc (16 pk_fma) -> VALU-bound.

#define M_DIM 2048
#define N_DIM 1024
#define K_DIM 1024

#define BM 32
#define BN 128
#define BK 64
#define NCHUNK (K_DIM / BK)   // 16

typedef unsigned u32;

// exact E4M3 (exp=4, man=3) quantization of an fp32 value, result fp32
__device__ __forceinline__ float quant_e4m3(float v) {
  unsigned au = __float_as_uint(v) & 0x7fffffffu;
  if (au == 0u) return v;                 // +-0
  int e = (int)(au >> 23) - 127;          // floor(log2|v|) for normals
  if (e < -6) e = -6;                     // fp32 subnorms hit the clamp too
  float s  = __uint_as_float((unsigned)(130 - e) << 23);  // 2^(3-e), exact
  float is = __uint_as_float((unsigned)(124 + e) << 23);  // 2^(e-3), exact
  float r = rintf(v * s) * is;            // RNE (half-to-even), all steps exact
  return fminf(240.f, fmaxf(-240.f, r));
}

// ---------- fused prep ----------
// blocks [0,2048): x [M][K] -> xPw[M/8][K/2][8]:
//   u32 at (m>>3, tp, m&7) = {q(x[m][2tp]), q(x[m][2tp+1])}
// blocks [2048,3072): w [N][K] -> wP[K/2][N/2][2]:
//   (tp, np) -> { h2(q(w[2np][2tp]), q(w[2np+1][2tp])),
//                 h2(q(w[2np][2tp+1]), q(w[2np+1][2tp+1])) }
__global__ __launch_bounds__(256) void prep_kernel(const float* __restrict__ x,
                                                   const float* __restrict__ w,
                                                   u32* __restrict__ xPw,
                                                   u32* __restrict__ wP) {
  __shared__ float tile[32][33];
  const int tx = threadIdx.x & 31;
  const int ty = threadIdx.x >> 5;
  if (blockIdx.x < 2048) {
    const int c0 = (blockIdx.x & 31) * 32;   // k offset
    const int r0 = (blockIdx.x >> 5) * 32;   // m offset
#pragma unroll
    for (int i = 0; i < 4; i++) {
      int r = r0 + ty + i * 8;
      tile[ty + i * 8][tx] = quant_e4m3(x[(size_t)r * K_DIM + c0 + tx]);
    }
    __syncthreads();
#pragma unroll
    for (int i = 0; i < 2; i++) {
      int tl = ty + i * 8;                   // k-pair local 0..15
      u32 lo = (u32)__half_as_ushort(__float2half(tile[tx][2 * tl]));
      u32 hi = (u32)__half_as_ushort(__float2half(tile[tx][2 * tl + 1]));
      xPw[(size_t)(r0 / 8 + (tx >> 3)) * (K_DIM / 2 * 8) +
          (c0 / 2 + tl) * 8 + (tx & 7)] = lo | (hi << 16);
    }
  } else {
    const int b = blockIdx.x - 2048;
    const int k0 = (b & 31) * 32;
    const int n0 = (b >> 5) * 32;
#pragma unroll
    for (int i = 0; i < 4; i++) {
      int n = n0 + ty + i * 8;
      tile[ty + i * 8][tx] = quant_e4m3(w[(size_t)n * K_DIM + k0 + tx]);   // [n_local][k_local]
    }
    __syncthreads();
    const int tpl = threadIdx.x >> 4;     // 0..15 k-pair local
    const int npl = threadIdx.x & 15;     // 0..15 n-pair local
    u32 a0 = (u32)__half_as_ushort(__float2half(tile[2 * npl][2 * tpl])) |
             ((u32)__half_as_ushort(__float2half(tile[2 * npl + 1][2 * tpl])) << 16);
    u32 a1 = (u32)__half_as_ushort(__float2half(tile[2 * npl][2 * tpl + 1])) |
             ((u32)__half_as_ushort(__float2half(tile[2 * npl + 1][2 * tpl + 1])) << 16);
    uint2 o; o.x = a0; o.y = a1;
    *reinterpret_cast<uint2*>(wP + (size_t)(k0 / 2 + tpl) * N_DIM + n0 + 2 * npl) = o;
  }
}

// ---------- GEMM ----------

__device__ __forceinline__ void gld16(const void* g, void* l) {
  __builtin_amdgcn_global_load_lds((const __attribute__((address_space(1))) u32*)g,
                                   (__attribute__((address_space(3))) u32*)l, 16, 0, 0);
}

// acc = pk_fma(splat(x.lo), w, acc)  -- k0 of the packed pair
__device__ __forceinline__ void pkfma_lo(u32& acc, u32 x, u32 w) {
  asm("v_pk_fma_f16 %0, %1, %2, %0 op_sel:[0,0,0] op_sel_hi:[0,1,1]"
      : "+v"(acc) : "v"(x), "v"(w));
}
// acc = pk_fma(splat(x.hi), w, acc)  -- k1 of the packed pair
__device__ __forceinline__ void pkfma_hi(u32& acc, u32 x, u32 w) {
  asm("v_pk_fma_f16 %0, %1, %2, %0 op_sel:[1,0,0] op_sel_hi:[1,1,1]"
      : "+v"(acc) : "v"(x), "v"(w));
}

// xPw [M/8][K/2][8] u32, wP [K/2][N/2][2] u32, b [N] fp32, out [M][N] fp32.
// 256 threads = 4 waves; block tile 32(m) x 128(n); wave = 8m x 128n;
// lane = one n-pair (2n) x 8m. x is wave-uniform, global-prefetched.
__global__ __launch_bounds__(256, 2) void gemm_qfma(const u32* __restrict__ xPw,
                                                    const u32* __restrict__ wP,
                                                    const float* __restrict__ b,
                                                    float* __restrict__ outp) {
  __shared__ __align__(16) u32 wsh[2][BK / 2][BN];   // [buf][tp][np*2+j], 16 KB x2
  const int tid = threadIdx.x;
  const int lane = tid & 63;        // n-pair index
  const int wid = tid >> 6;         // 0..3 m-group
  const int bn0 = blockIdx.x * BN;  // n offset (also u32 col offset in wP rows)
  const int bm0 = blockIdx.y * BM;

  u32 acc[8];
#pragma unroll
  for (int i = 0; i < 8; i++) acc[i] = 0u;

  // w staging: linear LDS (wave-uniform base + lane*16), per-lane global src
  const u32* wsrc = wP + (size_t)(tid >> 5) * N_DIM + bn0 + ((tid & 31) << 2);
  char* const wldst = (char*)&wsh[0][0][0] + tid * 16;

  auto stage = [&](int ch, int buf) {
    const u32* wp = wsrc + (size_t)ch * (BK / 2) * N_DIM;
    char* wl = wldst + buf * (BK / 2) * BN * 4;
#pragma unroll
    for (int p = 0; p < 4; p++)                       // 32 x 128 u32, 16 KB
      gld16(wp + (size_t)(p * 8) * N_DIM, wl + p * 4096);
  };

  // x stream: this wave's 8 m-rows, contiguous 16 KB over all k-pairs
  const u32* const xw = xPw + (size_t)(blockIdx.y * 4 + wid) * (K_DIM / 2 * 8);

  uint4 xA[16], xB[16];   // ping-pong: one 8-k-pair group each (64 u32)

#define LOADG(dst, g)                                                   \
  {                                                                     \
    const uint4* p_ = reinterpret_cast<const uint4*>(xw + (size_t)(g) * 64); \
    _Pragma("unroll") for (int i_ = 0; i_ < 16; i_++) dst[i_] = p_[i_]; \
  }

  auto computeG = [&](const uint4 (&xb)[16], int buf, int gc) {
#pragma unroll
    for (int j = 0; j < 8; j++) {            // k-pair: k0=.., k1=..
      const uint2 wv = *reinterpret_cast<const uint2*>(&wsh[buf][gc * 8 + j][lane << 1]);
      const uint4 xl = xb[2 * j];            // m0..3
      const uint4 xh = xb[2 * j + 1];        // m4..7
      // strict k order per accumulator: all k0 updates, then all k1 updates
      pkfma_lo(acc[0], xl.x, wv.x); pkfma_lo(acc[1], xl.y, wv.x);
      pkfma_lo(acc[2], xl.z, wv.x); pkfma_lo(acc[3], xl.w, wv.x);
      pkfma_lo(acc[4], xh.x, wv.x); pkfma_lo(acc[5], xh.y, wv.x);
      pkfma_lo(acc[6], xh.z, wv.x); pkfma_lo(acc[7], xh.w, wv.x);
      pkfma_hi(acc[0], xl.x, wv.y); pkfma_hi(acc[1], xl.y, wv.y);
      pkfma_hi(acc[2], xl.z, wv.y); pkfma_hi(acc[3], xl.w, wv.y);
      pkfma_hi(acc[4], xh.x, wv.y); pkfma_hi(acc[5], xh.y, wv.y);
      pkfma_hi(acc[6], xh.z, wv.y); pkfma_hi(acc[7], xh.w, wv.y);
    }
  };

  stage(0, 0);
  LOADG(xA, 0);
  __syncthreads();
#pragma unroll 1
  for (int ch = 0; ch < NCHUNK; ch++) {
    if (ch + 1 < NCHUNK) stage(ch + 1, (ch + 1) & 1);
    const int g0 = ch * 4;
    // note: LOADG(xA, g0+4) at ch==15 overreads 256 B into wP (allocated,
    // never consumed) -- keeps the pipeline branch-free.
    LOADG(xB, g0 + 1); computeG(xA, ch & 1, 0);
    LOADG(xA, g0 + 2); computeG(xB, ch & 1, 1);
    LOADG(xB, g0 + 3); computeG(xA, ch & 1, 2);
    LOADG(xA, g0 + 4); computeG(xB, ch & 1, 3);
    __syncthreads();
  }

  // epilogue: out = fp16RNE(acc + q8(b)), stored fp32 (fp32 add exact here)
  const int nc = bn0 + (lane << 1);
  const float bq0 = quant_e4m3(b[nc]);
  const float bq1 = quant_e4m3(b[nc + 1]);
#pragma unroll
  for (int i = 0; i < 8; i++) {
    __half2 a = *reinterpret_cast<__half2*>(&acc[i]);
    float2 o;
    o.x = __half2float(__float2half(__low2float(a)  + bq0));
    o.y = __half2float(__float2half(__high2float(a) + bq1));
    *reinterpret_cast<float2*>(outp + (size_t)(bm0 + (wid << 3) + i) * N_DIM + nc) = o;
  }
}

extern "C" void kernel_launch(void* const* d_in, const int* in_sizes, int n_in,
                              void* d_out, int out_size, void* d_ws, size_t ws_size,
                              hipStream_t stream) {
  const float* x = (const float*)d_in[0];   // [2048][1024]
  const float* w = (const float*)d_in[1];   // [1024][1024] (out_f, in_f)
  const float* b = (const float*)d_in[2];   // [1024]
  float* outp = (float*)d_out;              // [2048][1024] fp32

  char* ws = (char*)d_ws;
  u32* xPw = (u32*)ws;                       // [M/8][K/2][8] u32, 4 MiB
  u32* wP = (u32*)(ws + (size_t)(4 << 20));  // [K/2][N/2][2] u32, 2 MiB

  hipLaunchKernelGGL(prep_kernel, dim3(2048 + 1024), dim3(256), 0, stream,
                     x, w, xPw, wP);
  hipLaunchKernelGGL(gemm_qfma, dim3(N_DIM / BN, M_DIM / BM), dim3(256), 0, stream,
                     xPw, wP, b, outp);
}

// Round 7
// 110.270 us; speedup vs baseline: 1.2356x; 1.2356x over previous
//
#include <hip/hip_runtime.h>
#include <hip/hip_fp16.h>

// QLinear with per-k fp16 requantized accumulation (mptorch fma semantics).
// out = q16( q16_scan_fma( q8(x) @ q8(W)^T ) + q8(b) )
//
// Round-7: round-3 skeleton (proven safe/correct), wave retiled to 32m x 32n
// (lane 4m x 4n, 8x8 lanes) so BOTH operand reads are 8-distinct-address
// ds_read_b128 (128 B distinct, banks 0..31 once, 8-way broadcast ~4-5 cyc)
// instead of round-3's 64-lane-distinct w read (~12+ cyc). LDS/CU/k-pair
// ~80 cyc vs VALU wall 64 -> near-VALU-bound. No asm loads (rounds 5/6
// crashed: asm-volatile prefetch regs can be reallocated before the wait;
// landing loads clobber live registers -> memory fault).

#define M_DIM 2048
#define N_DIM 1024
#define K_DIM 1024

#define BM 64
#define BN 64
#define BK 64
#define NCHUNK (K_DIM / BK)   // 16

typedef unsigned u32;

// exact E4M3 (exp=4, man=3) quantization of an fp32 value, result fp32
__device__ __forceinline__ float quant_e4m3(float v) {
  unsigned au = __float_as_uint(v) & 0x7fffffffu;
  if (au == 0u) return v;                 // +-0
  int e = (int)(au >> 23) - 127;          // floor(log2|v|) for normals
  if (e < -6) e = -6;                     // fp32 subnorms hit the clamp too
  float s  = __uint_as_float((unsigned)(130 - e) << 23);  // 2^(3-e), exact
  float is = __uint_as_float((unsigned)(124 + e) << 23);  // 2^(e-3), exact
  float r = rintf(v * s) * is;            // RNE (half-to-even), all steps exact
  return fminf(240.f, fmaxf(-240.f, r));
}

// ---------- fused prep ----------
// blocks [0,2048): x [M][K] -> xP[K/2][M], u32 = {q(x[m][2t]), q(x[m][2t+1])}
// blocks [2048,3072): w [N][K] -> wP[K/2][N/2][2] u32:
//   (t, np) -> { h2(q(w[2np][2t]),  q(w[2np+1][2t])),
//                h2(q(w[2np][2t+1]),q(w[2np+1][2t+1])) }
//   -> uint4 at col 4c covers {k0,k1} x n-pairs {2c,2c+1} (4 n, 2 k).
__global__ __launch_bounds__(256) void prep_kernel(const float* __restrict__ x,
                                                   const float* __restrict__ w,
                                                   u32* __restrict__ xP,
                                                   u32* __restrict__ wP) {
  __shared__ float tile[32][33];
  const int tx = threadIdx.x & 31;
  const int ty = threadIdx.x >> 5;
  if (blockIdx.x < 2048) {
    const int c0 = (blockIdx.x & 31) * 32;   // k offset
    const int r0 = (blockIdx.x >> 5) * 32;   // m offset
#pragma unroll
    for (int i = 0; i < 4; i++) {
      int r = r0 + ty + i * 8;
      tile[ty + i * 8][tx] = quant_e4m3(x[(size_t)r * K_DIM + c0 + tx]);
    }
    __syncthreads();
#pragma unroll
    for (int i = 0; i < 2; i++) {
      int tl = ty + i * 8;                   // k-pair local 0..15
      u32 lo = (u32)__half_as_ushort(__float2half(tile[tx][2 * tl]));
      u32 hi = (u32)__half_as_ushort(__float2half(tile[tx][2 * tl + 1]));
      xP[(size_t)(c0 / 2 + tl) * M_DIM + r0 + tx] = lo | (hi << 16);
    }
  } else {
    const int b = blockIdx.x - 2048;
    const int k0 = (b & 31) * 32;
    const int n0 = (b >> 5) * 32;
#pragma unroll
    for (int i = 0; i < 4; i++) {
      int n = n0 + ty + i * 8;
      tile[ty + i * 8][tx] = quant_e4m3(w[(size_t)n * K_DIM + k0 + tx]);  // [n_local][k_local]
    }
    __syncthreads();
    const int tpl = threadIdx.x >> 4;     // 0..15 k-pair local
    const int npl = threadIdx.x & 15;     // 0..15 n-pair local
    u32 a0 = (u32)__half_as_ushort(__float2half(tile[2 * npl][2 * tpl])) |
             ((u32)__half_as_ushort(__float2half(tile[2 * npl + 1][2 * tpl])) << 16);
    u32 a1 = (u32)__half_as_ushort(__float2half(tile[2 * npl][2 * tpl + 1])) |
             ((u32)__half_as_ushort(__float2half(tile[2 * npl + 1][2 * tpl + 1])) << 16);
    uint2 o; o.x = a0; o.y = a1;
    *reinterpret_cast<uint2*>(wP + (size_t)(k0 / 2 + tpl) * N_DIM + n0 + 2 * npl) = o;
  }
}

// ---------- GEMM ----------

__device__ __forceinline__ void gld16(const void* g, void* l) {
  __builtin_amdgcn_global_load_lds((const __attribute__((address_space(1))) u32*)g,
                                   (__attribute__((address_space(3))) u32*)l, 16, 0, 0);
}

// acc = pk_fma(splat(x.lo), w, acc)  -- k0 of the packed pair
__device__ __forceinline__ void pkfma_lo(u32& acc, u32 x, u32 w) {
  asm("v_pk_fma_f16 %0, %1, %2, %0 op_sel:[0,0,0] op_sel_hi:[0,1,1]"
      : "+v"(acc) : "v"(x), "v"(w));
}
// acc = pk_fma(splat(x.hi), w, acc)  -- k1 of the packed pair
__device__ __forceinline__ void pkfma_hi(u32& acc, u32 x, u32 w) {
  asm("v_pk_fma_f16 %0, %1, %2, %0 op_sel:[1,0,0] op_sel_hi:[1,1,1]"
      : "+v"(acc) : "v"(x), "v"(w));
}

// xP [K/2][M] u32, wP [K/2][N] u32 (n-pair interleaved), b [N] fp32,
// out [M][N] fp32.  256 threads = 4 waves (2x2); block tile 64m x 64n;
// wave tile 32m x 32n; lane tile 4m x 4n (tml=lane>>3, tnl=lane&7).
__global__ __launch_bounds__(256, 2) void gemm_qfma(const u32* __restrict__ xP,
                                                    const u32* __restrict__ wP,
                                                    const float* __restrict__ b,
                                                    float* __restrict__ outp) {
  __shared__ __align__(16) u32 xs[2][BK / 2][BM];   // 2 x 32 x 64 u32 = 16 KB
  __shared__ __align__(16) u32 ws[2][BK / 2][BN];   // 2 x 32 x 64 u32 = 16 KB
  const int tid = threadIdx.x;
  const int lane = tid & 63;
  const int wv = tid >> 6;          // 0..3
  const int wr = wv >> 1;           // m half (0,1)
  const int wc = wv & 1;            // n half (0,1)
  const int tml = lane >> 3;        // 0..7
  const int tnl = lane & 7;         // 0..7
  const int bn0 = blockIdx.x * BN;
  const int bm0 = blockIdx.y * BM;
  const int xoff = wr * 32 + tml * 4;   // u32 col in xs row
  const int woff = wc * 32 + tnl * 4;   // u32 col in ws row

  u32 acc[4][2];
#pragma unroll
  for (int i = 0; i < 4; i++) { acc[i][0] = 0u; acc[i][1] = 0u; }

  // staging: linear LDS (wave-uniform base + lane*16), per-lane global src.
  // per chunk: 32 rows x 64 u32 per operand = 8 KB = 2 passes x 256 thr x 16 B
  const int srow = tid >> 4;            // 0..15
  const int scol = (tid & 15) << 2;     // 0..60
  const u32* xsrc = xP + (size_t)srow * M_DIM + bm0 + scol;
  const u32* wsrc = wP + (size_t)srow * N_DIM + bn0 + scol;

  auto stage = [&](int ch, int buf) {
    const u32* xp = xsrc + (size_t)ch * (BK / 2) * M_DIM;
    const u32* wp = wsrc + (size_t)ch * (BK / 2) * N_DIM;
    char* xl = (char*)&xs[buf][0][0] + tid * 16;
    char* wl = (char*)&ws[buf][0][0] + tid * 16;
    gld16(xp, xl);
    gld16(xp + (size_t)16 * M_DIM, xl + 4096);
    gld16(wp, wl);
    gld16(wp + (size_t)16 * N_DIM, wl + 4096);
  };

  auto compute = [&](int buf) {
#pragma unroll
    for (int tp = 0; tp < BK / 2; tp++) {   // k-pair: k0=2tp, k1=2tp+1
      const uint4 xv = *reinterpret_cast<const uint4*>(&xs[buf][tp][xoff]);
      const uint4 wv4 = *reinterpret_cast<const uint4*>(&ws[buf][tp][woff]);
      // wv4 = {k0 n01, k1 n01, k0 n23, k1 n23}
      // strict k order per accumulator: all k0 updates, then all k1 updates
      pkfma_lo(acc[0][0], xv.x, wv4.x); pkfma_lo(acc[0][1], xv.x, wv4.z);
      pkfma_lo(acc[1][0], xv.y, wv4.x); pkfma_lo(acc[1][1], xv.y, wv4.z);
      pkfma_lo(acc[2][0], xv.z, wv4.x); pkfma_lo(acc[2][1], xv.z, wv4.z);
      pkfma_lo(acc[3][0], xv.w, wv4.x); pkfma_lo(acc[3][1], xv.w, wv4.z);
      pkfma_hi(acc[0][0], xv.x, wv4.y); pkfma_hi(acc[0][1], xv.x, wv4.w);
      pkfma_hi(acc[1][0], xv.y, wv4.y); pkfma_hi(acc[1][1], xv.y, wv4.w);
      pkfma_hi(acc[2][0], xv.z, wv4.y); pkfma_hi(acc[2][1], xv.z, wv4.w);
      pkfma_hi(acc[3][0], xv.w, wv4.y); pkfma_hi(acc[3][1], xv.w, wv4.w);
    }
  };

  stage(0, 0);
  __syncthreads();
#pragma unroll 1
  for (int ch = 0; ch < NCHUNK; ch += 2) {
    stage(ch + 1, 1);          // issue next chunk's loads before compute
    compute(0);
    __syncthreads();
    if (ch + 2 < NCHUNK) stage(ch + 2, 0);
    compute(1);
    __syncthreads();
  }

  // epilogue: out = fp16RNE(acc + q8(b)), stored fp32 (fp32 add exact here)
  const int nc = bn0 + wc * 32 + tnl * 4;
  float4 bq;
  bq.x = quant_e4m3(b[nc + 0]);
  bq.y = quant_e4m3(b[nc + 1]);
  bq.z = quant_e4m3(b[nc + 2]);
  bq.w = quant_e4m3(b[nc + 3]);
#pragma unroll
  for (int i = 0; i < 4; i++) {
    __half2 a0 = *reinterpret_cast<__half2*>(&acc[i][0]);  // n0,n1
    __half2 a1 = *reinterpret_cast<__half2*>(&acc[i][1]);  // n2,n3
    float4 o;
    o.x = __half2float(__float2half(__low2float(a0)  + bq.x));
    o.y = __half2float(__float2half(__high2float(a0) + bq.y));
    o.z = __half2float(__float2half(__low2float(a1)  + bq.z));
    o.w = __half2float(__float2half(__high2float(a1) + bq.w));
    *reinterpret_cast<float4*>(
        outp + (size_t)(bm0 + wr * 32 + tml * 4 + i) * N_DIM + nc) = o;
  }
}

extern "C" void kernel_launch(void* const* d_in, const int* in_sizes, int n_in,
                              void* d_out, int out_size, void* d_ws, size_t ws_size,
                              hipStream_t stream) {
  const float* x = (const float*)d_in[0];   // [2048][1024]
  const float* w = (const float*)d_in[1];   // [1024][1024] (out_f, in_f)
  const float* b = (const float*)d_in[2];   // [1024]
  float* outp = (float*)d_out;              // [2048][1024] fp32

  char* ws_ = (char*)d_ws;
  u32* xP = (u32*)ws_;                        // [K/2][M] u32, 4 MiB
  u32* wP = (u32*)(ws_ + (size_t)(4 << 20));  // [K/2][N] u32, 2 MiB

  hipLaunchKernelGGL(prep_kernel, dim3(2048 + 1024), dim3(256), 0, stream,
                     x, w, xP, wP);
  hipLaunchKernelGGL(gemm_qfma, dim3(N_DIM / BN, M_DIM / BM), dim3(256), 0, stream,
                     xP, wP, b, outp);
}